// Round 2
// baseline (221.034 us; speedup 1.0000x reference)
//
#include <hip/hip_runtime.h>

// SpikingLayer: T=64 sequential steps over [B=32, F=16384] fp32 state.
//   state = (x + state) - act
//   state = max(state + 1.0f, 0.0f) - 1.0f   // bit-exact relu(s+1)-1, NOT max(s,-1)
//   act   = state > 0 ? floor(state) : 0
// 134 MB in + 134 MB out => 42.7 us floor at 6.29 TB/s measured copy ceiling.
// Harness also runs 2x ~80us 536MB fills inside the timed region -> ~161us fixed.
//
// History (kernel-only estimates; total = kernel + ~161us fills):
// R2: float4, depth-2, 8 waves/CU   -> ~71 us
// R3: scalar, depth-8, 32 waves/CU  -> ~82 us (4 B/lane too narrow: vmem instr efficiency)
// R6: float4, depth-8 ring, NT      -> ~57 us (total 217.4)
// R7: float4, 8-step phase bursts   -> ~54 us (total 215.4) NEUTRAL: direction-flip
//     theory wrong; compiler waitcnt was already fine.
// R8 (this): occupancy test. float4 caps us at 8 waves/CU structurally
// (131072 threads). float2 = 8 B/lane (G13 sweet spot lower edge, 512 B/instr)
// doubles TLP to 16 waves/CU. If the gap to copy-ceiling is issue-coverage
// (bursty per-wave stalls at low wave count), this closes it; if width rules
// (R3 lesson), this regresses and we're at the mixed-stream HBM wall.

#define T_STEPS 64
#define NCHAINS (32 * 16384)       // B*F = 524288 independent chains
#define NCHAINS2 (NCHAINS / 2)     // float2 groups: 262144 threads
#define GROUP 8                    // steps per phase (8 x 8 B = 4 KB/wave bursts)

typedef float vfloat2 __attribute__((ext_vector_type(2)));

// All macro indices are literal constants after expansion -> everything stays in
// registers (runtime-indexed ext_vector arrays would go to scratch).

#define LOAD_GROUP(BUF, G)                                                      \
  {                                                                             \
    _Pragma("unroll")                                                           \
    for (int j = 0; j < GROUP; ++j)                                             \
      BUF[j] = __builtin_nontemporal_load(&in[((G) * GROUP + j) * NCHAINS2 + i]); \
  }

#define STEP_GROUP(BUF, G)                                                      \
  {                                                                             \
    vfloat2 ov[GROUP];                                                          \
    _Pragma("unroll")                                                           \
    for (int j = 0; j < GROUP; ++j) {                                           \
      vfloat2 x = BUF[j];                                                       \
      float xe[2] = {x.x, x.y};                                                 \
      _Pragma("unroll")                                                         \
      for (int e = 0; e < 2; ++e) {                                             \
        /* EXACT ref op order: s = (x + s) - a; s = max(s+1,0)-1; a = spikes */ \
        float sv = (xe[e] + s[e]) - a[e];                                       \
        sv = fmaxf(sv + 1.0f, 0.0f) - 1.0f;                                     \
        s[e] = sv;                                                              \
        a[e] = (sv > 0.0f) ? floorf(sv) : 0.0f;                                 \
      }                                                                         \
      vfloat2 av = {a[0], a[1]};                                                \
      ov[j] = av;                                                               \
    }                                                                           \
    _Pragma("unroll")                                                           \
    for (int j = 0; j < GROUP; ++j)                                             \
      __builtin_nontemporal_store(ov[j], &out[((G) * GROUP + j) * NCHAINS2 + i]); \
  }

__global__ __launch_bounds__(256) void spiking_kernel(
    const vfloat2* __restrict__ in, vfloat2* __restrict__ out) {
    const int i = blockIdx.x * blockDim.x + threadIdx.x;

    float s[2] = {0.f, 0.f};
    float a[2] = {0.f, 0.f};

    vfloat2 xa[GROUP], xb[GROUP];

    // Prologue: groups 0 and 1 in flight (16 loads, 8 KB/wave) before any compute.
    LOAD_GROUP(xa, 0);
    LOAD_GROUP(xb, 1);

    // Steady state: issue loads for g+1, then compute+store g.
    STEP_GROUP(xa, 0);
    LOAD_GROUP(xa, 2);
    STEP_GROUP(xb, 1);
    LOAD_GROUP(xb, 3);
    STEP_GROUP(xa, 2);
    LOAD_GROUP(xa, 4);
    STEP_GROUP(xb, 3);
    LOAD_GROUP(xb, 5);
    STEP_GROUP(xa, 4);
    LOAD_GROUP(xa, 6);
    STEP_GROUP(xb, 5);
    LOAD_GROUP(xb, 7);
    STEP_GROUP(xa, 6);
    STEP_GROUP(xb, 7);
}

extern "C" void kernel_launch(void* const* d_in, const int* in_sizes, int n_in,
                              void* d_out, int out_size, void* d_ws, size_t ws_size,
                              hipStream_t stream) {
    const vfloat2* in = (const vfloat2*)d_in[0];
    vfloat2* out = (vfloat2*)d_out;
    // 262144 threads / 256 = 1024 blocks -> 4 blocks/CU, 16 waves/CU
    // (float2 doubles TLP vs float4's structural 8 waves/CU cap)
    spiking_kernel<<<NCHAINS2 / 256, 256, 0, stream>>>(in, out);
}

// Round 3
// 218.012 us; speedup vs baseline: 1.0139x; 1.0139x over previous
//
#include <hip/hip_runtime.h>

// SpikingLayer: T=64 sequential steps over [B=32, F=16384] fp32 state.
//   state = (x + state) - act
//   state = max(state + 1.0f, 0.0f) - 1.0f   // bit-exact relu(s+1)-1, NOT max(s,-1)
//   act   = state > 0 ? floor(state) : 0
// 134 MB in + 134 MB out => 42.7 us floor at 6.29 TB/s measured copy ceiling.
// Harness also runs 2x ~80us 536MB write-only fills inside the timed region
// (~159us fixed, 6.76 TB/s — not controllable from the kernel).
//
// History (kernel-only estimates; total = kernel + ~159-161us fills):
// R2: float4, depth-2, 8 waves/CU   -> ~71 us
// R3: scalar, depth-8, 32 waves/CU  -> ~82 us (4 B/lane: vmem instr width rules)
// R6: float4, depth-8 ring, NT both -> ~57 us (total 217.4)
// R7: float4, 8-step phase bursts   -> ~54 us (total 215.4) burst shaping ~neutral
// R8: float2, 16 waves/CU           -> ~62 us (total 221.0) REGRESSED: width >
//     occupancy, monotone 4B<8B<16B. Occupancy falsified as the lever.
// R9 (this): NT-STORE ABLATION at fixed R7 structure. Our 4.97 TB/s vs the
// fills' 6.76 (regular stores) and m13 copy's 6.29: the untested delta is the
// nontemporal hint on stores. NT store = no-allocate -> acks from deep in the
// memory system and forfeits L2 write buffering, so HBM sees raw 50/50 R/W
// turnaround. Flip stores to plain L2-allocating; keep NT loads (no reuse,
// leaves L2 to the write stream).

#define T_STEPS 64
#define NCHAINS (32 * 16384)       // B*F = 524288 independent chains
#define NCHAINS4 (NCHAINS / 4)     // float4 groups: 131072 threads
#define GROUP 8                    // steps per phase (8 x 16 B = 8 KB/wave bursts)

typedef float vfloat4 __attribute__((ext_vector_type(4)));

// All macro indices are literal constants after expansion -> everything stays in
// registers (runtime-indexed ext_vector arrays would go to scratch).

#define LOAD_GROUP(BUF, G)                                                      \
  {                                                                             \
    _Pragma("unroll")                                                           \
    for (int j = 0; j < GROUP; ++j)                                             \
      BUF[j] = __builtin_nontemporal_load(&in[((G) * GROUP + j) * NCHAINS4 + i]); \
  }

#define STEP_GROUP(BUF, G)                                                      \
  {                                                                             \
    vfloat4 ov[GROUP];                                                          \
    _Pragma("unroll")                                                           \
    for (int j = 0; j < GROUP; ++j) {                                           \
      vfloat4 x = BUF[j];                                                       \
      float xe[4] = {x.x, x.y, x.z, x.w};                                       \
      _Pragma("unroll")                                                         \
      for (int e = 0; e < 4; ++e) {                                             \
        /* EXACT ref op order: s = (x + s) - a; s = max(s+1,0)-1; a = spikes */ \
        float sv = (xe[e] + s[e]) - a[e];                                       \
        sv = fmaxf(sv + 1.0f, 0.0f) - 1.0f;                                     \
        s[e] = sv;                                                              \
        a[e] = (sv > 0.0f) ? floorf(sv) : 0.0f;                                 \
      }                                                                         \
      vfloat4 av = {a[0], a[1], a[2], a[3]};                                    \
      ov[j] = av;                                                               \
    }                                                                           \
    _Pragma("unroll")                                                           \
    for (int j = 0; j < GROUP; ++j)                                             \
      out[((G) * GROUP + j) * NCHAINS4 + i] = ov[j];  /* REGULAR store: L2-allocating */ \
  }

__global__ __launch_bounds__(256) void spiking_kernel(
    const vfloat4* __restrict__ in, vfloat4* __restrict__ out) {
    const int i = blockIdx.x * blockDim.x + threadIdx.x;

    float s[4] = {0.f, 0.f, 0.f, 0.f};
    float a[4] = {0.f, 0.f, 0.f, 0.f};

    vfloat4 xa[GROUP], xb[GROUP];

    // Prologue: groups 0 and 1 in flight (16 loads, 16 KB/wave) before any compute.
    LOAD_GROUP(xa, 0);
    LOAD_GROUP(xb, 1);

    // Steady state: issue loads for g+1, then compute+store g.
    STEP_GROUP(xa, 0);
    LOAD_GROUP(xa, 2);
    STEP_GROUP(xb, 1);
    LOAD_GROUP(xb, 3);
    STEP_GROUP(xa, 2);
    LOAD_GROUP(xa, 4);
    STEP_GROUP(xb, 3);
    LOAD_GROUP(xb, 5);
    STEP_GROUP(xa, 4);
    LOAD_GROUP(xa, 6);
    STEP_GROUP(xb, 5);
    LOAD_GROUP(xb, 7);
    STEP_GROUP(xa, 6);
    STEP_GROUP(xb, 7);
}

extern "C" void kernel_launch(void* const* d_in, const int* in_sizes, int n_in,
                              void* d_out, int out_size, void* d_ws, size_t ws_size,
                              hipStream_t stream) {
    const vfloat4* in = (const vfloat4*)d_in[0];
    vfloat4* out = (vfloat4*)d_out;
    // 131072 threads / 256 = 512 blocks -> 2 blocks/CU, 8 waves/CU (structural cap:
    // each float4 chain is serial over T; 16 B/lane is the max vmem width)
    spiking_kernel<<<NCHAINS4 / 256, 256, 0, stream>>>(in, out);
}